// Round 5
// baseline (368.099 us; speedup 1.0000x reference)
//
#include <hip/hip_runtime.h>
#include <hip/hip_bf16.h>
#include <math.h>

#define BB   64
#define TT   32
#define CC   256
#define KK   16384
#define G1c  4.0f
#define G2c  5.0f
#define G3c  10.0f
#define INV_T 20.0f
#define EPSF 1e-8f

// Workspace layout (floats)
#define WS_SIM 0
#define WS_S0  4096
#define WS_S2  8192
#define WS_CN  12288
#define WS_RN  28672
#define WS_CAN 45056
#define WS_RAN 61440
#define WS_QN  77824
#define WS_PM  79872                 // [2][128 ch][64 row]
#define WS_PS  (WS_PM + 16384)
#define WS_CNT  (WS_PS + 16384)      // [256][64] transposed codes
#define WS_RNT  (WS_CNT + 16384)
#define WS_CANT (WS_RNT + 16384)
#define WS_RANT (WS_CANT + 16384)
#define WS_F32_TOTAL (WS_RANT + 16384)

// bf16 arrays (shorts), after the f32 section
#define CTXT_ELEMS (64*320*256)    // ctxT[j][s(320)][c]
#define CTXC_ELEMS (64*256*320)    // ctxC[j][c][s(320)]
#define WQ_ELEMS   (64*32*256)     // wq[i][t][c]
#define CNRN_OFF   (CTXT_ELEMS + CTXC_ELEMS + WQ_ELEMS)  // [2][64][256]

#define SC_STR 260   // ctx_sc row stride (shorts): 130 dw ≡ 2 mod 4 -> conflict-free

typedef __attribute__((ext_vector_type(8))) short short8;
typedef __attribute__((ext_vector_type(4))) short short4v;
typedef __attribute__((ext_vector_type(4))) float float4v;

__device__ __forceinline__ float4v mfma_bf16(short8 a, short8 b, float4v c) {
    return __builtin_amdgcn_mfma_f32_16x16x32_bf16(a, b, c, 0, 0, 0);
}

__device__ __forceinline__ short f2bf(float f) {
    union { float f; unsigned u; } x; x.f = f;
    unsigned r = x.u + 0x7FFFu + ((x.u >> 16) & 1u);
    return (short)(r >> 16);
}

// LDS 8-short load as 2 x b64 (rows 8B-aligned)
__device__ __forceinline__ short8 ld8(const short* p) {
    short4v lo = *(const short4v*)p;
    short4v hi = *(const short4v*)(p + 4);
    short8 r = {lo[0],lo[1],lo[2],lo[3],hi[0],hi[1],hi[2],hi[3]};
    return r;
}

// ---------------------------------------------------------------------------
// Prep. grid: [0,256) codes | [256,320) qn | [320,1600) ctxT |
//             [1600,1984) ctxC | [1984,2048) wq
// ---------------------------------------------------------------------------
__global__ __launch_bounds__(256) void prep_kernel(
    const float* __restrict__ cnn, const float* __restrict__ rnn,
    const float* __restrict__ img, const float* __restrict__ wemb,
    const float* __restrict__ cnnA, const float* __restrict__ rnnA,
    float* __restrict__ W)
{
    int bid = blockIdx.x, tid = threadIdx.x;
    short* B16 = (short*)(W + WS_F32_TOTAL);
    short* ctxT = B16;
    short* ctxC = B16 + CTXT_ELEMS;
    short* wq   = B16 + CTXT_ELEMS + CTXC_ELEMS;
    short* cnrn = B16 + CNRN_OFF;

    if (bid < 256) {
        int mat = bid >> 6, row = bid & 63;
        const float* src = (mat==0)? cnn : (mat==1)? rnn : (mat==2)? cnnA : rnnA;
        float* dst  = W + ((mat==0)? WS_CN  : (mat==1)? WS_RN  : (mat==2)? WS_CAN  : WS_RAN);
        float* dstT = W + ((mat==0)? WS_CNT : (mat==1)? WS_RNT : (mat==2)? WS_CANT : WS_RANT);
        float v = src[row*256 + tid];
        float ss = v*v;
        for (int o=1;o<64;o<<=1) ss += __shfl_xor(ss,o);
        __shared__ float sc[4];
        if ((tid&63)==0) sc[tid>>6] = ss;
        __syncthreads();
        float tot = sc[0]+sc[1]+sc[2]+sc[3];
        float inv = 1.0f / fmaxf(sqrtf(tot), EPSF);
        float nv = v*inv;
        dst[row*256+tid] = nv;
        dstT[tid*64+row] = nv;
        if (mat < 2) cnrn[(mat*64+row)*256 + tid] = f2bf(nv);
    } else if (bid < 320) {
        int i = bid - 256;
        int t = tid >> 3, k = tid & 7;
        const float* wp = wemb + (i*32 + t)*256 + k*32;
        float ss = 0.f;
        for (int c=0;c<32;c++){ float v = wp[c]; ss += v*v; }
        ss += __shfl_xor(ss,1); ss += __shfl_xor(ss,2); ss += __shfl_xor(ss,4);
        if (k==0) W[WS_QN + i*32 + t] = sqrtf(ss);
    } else if (bid < 1600) {
        int b3 = bid - 320; int j = b3 / 20, mt = b3 % 20, s0 = mt*16;
        __shared__ float tile[16*257];
        for (int idx = tid; idx < 4096; idx += 256) {
            int c = idx >> 4, sl = idx & 15, s = s0 + sl;
            float v = (s < 289) ? img[((size_t)(j*256 + c))*289 + s] : 0.0f;
            tile[sl*257 + c] = v;
        }
        __syncthreads();
        for (int idx = tid; idx < 4096; idx += 256) {
            int orr = idx >> 8, c = idx & 255;
            ctxT[((size_t)(j*320 + s0 + orr))*256 + c] = f2bf(tile[orr*257 + c]);
        }
    } else if (bid < 1984) {
        for (size_t idx = (size_t)(bid-1600)*256 + tid; idx < (size_t)CTXC_ELEMS; idx += (size_t)384*256) {
            int s = (int)(idx % 320); size_t rem = idx / 320;
            int c = (int)(rem & 255); int jj = (int)(rem >> 8);
            float v = (s < 289) ? img[((size_t)(jj*256 + c))*289 + s] : 0.0f;
            ctxC[idx] = f2bf(v);
        }
    } else {
        for (int idx = (bid-1984)*256 + tid; idx < WQ_ELEMS; idx += 64*256) {
            wq[idx] = f2bf(wemb[idx]);
        }
    }
}

// ---------------------------------------------------------------------------
// Fused attn + moco + smat.
// bid < 2048: attention (j = bid>>5, i-pair = bid&31)
// bid in [2048,2304): moco MFMA (mu x 128 chunks of 128 cols)
// bid in [2304,2368): smat
// ---------------------------------------------------------------------------
__global__ __launch_bounds__(256, 3) void attn_moco_kernel(
    const float* __restrict__ queue, const float* __restrict__ queueIm,
    float* __restrict__ W)
{
    __shared__ short ctx_sc[32*SC_STR];            // 16640 B
    __shared__ short eTile[2][2][32][36];          // 9216 B (double-buffered)
    __shared__ float Dp[4][32], Np[4][32];
    __shared__ float wn2P[4][2][2][16];
    __shared__ float redm[4][64], reds[4][64];     // moco
    __shared__ float sa0[256], sa1[256];           // smat
    __shared__ float part[2][64][4];

    int bid = blockIdx.x, tid = threadIdx.x;
    int lane = tid & 63, wave = tid >> 6;
    int lo16 = lane & 15, quad = lane >> 4;

    const short* B16 = (const short*)(W + WS_F32_TOTAL);

    if (bid < 2048) {
        // ================= attention =================
        const short* ctxT = B16;
        const short* ctxC = B16 + CTXT_ELEMS;
        const short* wq   = B16 + CTXT_ELEMS + CTXC_ELEMS;

        int j = bid >> 5, ip = bid & 31;
        int i_l = wave >> 1, mt = wave & 1;     // wave -> (i_local, s-Mtile)
        int i_g = ip*2 + i_l;

        // wq fragments for this wave's i, BOTH t-halves (in VGPRs)
        short8 bq[2][8];
        {
            const short* p = wq + i_g*8192;
            #pragma unroll
            for (int nt2=0;nt2<2;nt2++)
                #pragma unroll
                for (int kk=0;kk<8;kk++)
                    bq[nt2][kk] = *(const short8*)(p + (nt2*16+lo16)*256 + kk*32 + quad*8);
        }

        float4v wacc[4][4];
        #pragma unroll
        for (int cm=0;cm<4;cm++)
            #pragma unroll
            for (int cb=0;cb<4;cb++) wacc[cm][cb] = (float4v){0.f,0.f,0.f,0.f};
        float D0=0.f, D1=0.f, N0=0.f, N1=0.f;

        const short* ctxTj = ctxT + (size_t)j * (320*256);
        const short* ctxCj = ctxC + (size_t)j * (256*320);
        int s_row = tid >> 3, c0s = (tid & 7)*32;
        int srow_base = mt*16 + quad*4;         // this lane's s rows (+r) in tile

        // prefetch tile 0 of ctx_sc
        short8 pf[4];
        {
            const short* g = ctxTj + s_row*256 + c0s;
            #pragma unroll
            for (int m=0;m<4;m++) pf[m] = *(const short8*)(g + m*8);
        }

        for (int tile = 0; tile < 10; tile++) {
            // stage prefetched regs -> ctx_sc (b64 writes)
            {
                short* d = ctx_sc + s_row*SC_STR + c0s;
                #pragma unroll
                for (int k=0;k<8;k++) {
                    short4v w = { pf[k>>1][(k&1)*4+0], pf[k>>1][(k&1)*4+1],
                                  pf[k>>1][(k&1)*4+2], pf[k>>1][(k&1)*4+3] };
                    *(short4v*)(d + k*4) = w;
                }
            }
            __syncthreads();                     // B1: stores visible
            // prefetch next ctx_sc tile
            if (tile < 9) {
                const short* g = ctxTj + ((tile+1)*32 + s_row)*256 + c0s;
                #pragma unroll
                for (int m=0;m<4;m++) pf[m] = *(const short8*)(g + m*8);
            }
            // wC A-frags from global ctxC (independent -> issued early)
            short8 wa[4];
            #pragma unroll
            for (int cm=0;cm<4;cm++)
                wa[cm] = *(const short8*)(ctxCj + (size_t)((wave*4+cm)*16+lo16)*320 + tile*32 + quad*8);

            // scores MFMA: this wave's s-Mtile, all 32 t
            float4v a0 = {0.f,0.f,0.f,0.f}, a1 = {0.f,0.f,0.f,0.f};
            {
                const short* ar = ctx_sc + (mt*16 + lo16)*SC_STR + quad*8;
                #pragma unroll
                for (int kk=0;kk<8;kk++) {
                    short8 a = ld8(ar + kk*32);
                    a0 = mfma_bf16(a, bq[0][kk], a0);
                    a1 = mfma_bf16(a, bq[1][kk], a1);
                }
            }
            // in-register softmax over t per s-row; e -> eTile; D/N accum
            int eb = tile & 1;
            #pragma unroll
            for (int r=0;r<4;r++) {
                float mx = fmaxf(a0[r], a1[r]);
                mx = fmaxf(mx, __shfl_xor(mx,1));
                mx = fmaxf(mx, __shfl_xor(mx,2));
                mx = fmaxf(mx, __shfl_xor(mx,4));
                mx = fmaxf(mx, __shfl_xor(mx,8));
                float e0 = __expf(a0[r]-mx), e1 = __expf(a1[r]-mx);
                float z = e0 + e1;
                z += __shfl_xor(z,1); z += __shfl_xor(z,2);
                z += __shfl_xor(z,4); z += __shfl_xor(z,8);
                float rinv = 1.0f/z;
                int s_local = srow_base + r;
                int sg = tile*32 + s_local;
                float ev0 = 0.f, ev1 = 0.f;
                if (sg < 289) {
                    ev0 = __expf(G1c*e0*rinv);
                    ev1 = __expf(G1c*e1*rinv);
                    D0 += ev0; N0 += ev0*a0[r];
                    D1 += ev1; N1 += ev1*a1[r];
                }
                eTile[eb][i_l][lo16][s_local]    = f2bf(ev0);
                eTile[eb][i_l][16+lo16][s_local] = f2bf(ev1);
            }
            __syncthreads();                     // B2: eTile visible, ctx_sc reads done
            // wC MFMA: K=32 (one step), 4 Mtiles x 4 combos, B from eTile
            {
                short8 bf0 = ld8(&eTile[eb][0][lo16][quad*8]);
                short8 bf1 = ld8(&eTile[eb][0][16+lo16][quad*8]);
                short8 bf2 = ld8(&eTile[eb][1][lo16][quad*8]);
                short8 bf3 = ld8(&eTile[eb][1][16+lo16][quad*8]);
                #pragma unroll
                for (int cm=0;cm<4;cm++) {
                    wacc[cm][0] = mfma_bf16(wa[cm], bf0, wacc[cm][0]);
                    wacc[cm][1] = mfma_bf16(wa[cm], bf1, wacc[cm][1]);
                    wacc[cm][2] = mfma_bf16(wa[cm], bf2, wacc[cm][2]);
                    wacc[cm][3] = mfma_bf16(wa[cm], bf3, wacc[cm][3]);
                }
            }
            // no barrier here: next tile writes the other eTile buffer
        }

        // D/N reduce over quads, publish per wave
        D0 += __shfl_xor(D0,16); D0 += __shfl_xor(D0,32);
        D1 += __shfl_xor(D1,16); D1 += __shfl_xor(D1,32);
        N0 += __shfl_xor(N0,16); N0 += __shfl_xor(N0,32);
        N1 += __shfl_xor(N1,16); N1 += __shfl_xor(N1,32);
        if (lane < 16) {
            Dp[wave][lane] = D0; Dp[wave][16+lane] = D1;
            Np[wave][lane] = N0; Np[wave][16+lane] = N1;
        }
        // wn2 partials from wacc
        #pragma unroll
        for (int cb=0;cb<4;cb++) {
            float ss = 0.f;
            #pragma unroll
            for (int cm=0;cm<4;cm++)
                #pragma unroll
                for (int r=0;r<4;r++){ float v = wacc[cm][cb][r]; ss += v*v; }
            ss += __shfl_xor(ss,16);
            ss += __shfl_xor(ss,32);
            if (quad==0) wn2P[wave][cb>>1][cb&1][lo16] = ss;
        }
        __syncthreads();

        // epilogue
        if (tid < 64) {
            int i_f = tid >> 5, t = tid & 31;
            int nt2 = t >> 4, lo = t & 15;
            float w2 = wn2P[0][i_f][nt2][lo] + wn2P[1][i_f][nt2][lo]
                     + wn2P[2][i_f][nt2][lo] + wn2P[3][i_f][nt2][lo];
            float D = Dp[i_f*2][t] + Dp[i_f*2+1][t];
            float N = Np[i_f*2][t] + Np[i_f*2+1][t];
            int i_gf = ip*2 + i_f;
            float qv = W[WS_QN + i_gf*32 + t];
            float numS = N/D;
            float wnS = sqrtf(w2)/D;
            float v = G2c * (numS / fmaxf(qv*wnS, EPSF));
            float mx = v;
            for (int o=1;o<32;o<<=1) mx = fmaxf(mx, __shfl_xor(mx,o));
            float e = __expf(v-mx);
            for (int o=1;o<32;o<<=1) e += __shfl_xor(e,o);
            if (t==0) W[WS_SIM + i_gf*64 + j] = mx + __logf(e);
        }
    } else if (bid < 2304) {
        // ================= moco =================
        int bid2 = bid - 2048;
        int mu = bid2 >> 7, ch = bid2 & 127;
        const float* Q = mu ? queueIm : queue;
        const short* Abf = B16 + CNRN_OFF + mu*16384;

        short8 afr[4][8];
        #pragma unroll
        for (int mt=0;mt<4;mt++)
            #pragma unroll
            for (int kk=0;kk<8;kk++)
                afr[mt][kk] = *(const short8*)(Abf + (mt*16+lo16)*256 + kk*32 + quad*8);

        float m16[16], s16[16];
        #pragma unroll
        for (int u=0;u<16;u++){ m16[u] = -1e30f; s16[u] = 0.f; }

        for (int t4 = 0; t4 < 2; t4++) {
            int colb = ch*128 + (wave*2 + t4)*16;
            float4v acc[4];
            #pragma unroll
            for (int mt=0;mt<4;mt++) acc[mt] = (float4v){0.f,0.f,0.f,0.f};
            for (int ks = 0; ks < 8; ks++) {
                short8 bfr;
                #pragma unroll
                for (int jj=0;jj<8;jj++) {
                    float bv = Q[(size_t)(ks*32 + quad*8 + jj)*KK + colb + lo16];
                    bfr[jj] = f2bf(bv);
                }
                #pragma unroll
                for (int mt=0;mt<4;mt++) acc[mt] = mfma_bf16(afr[mt][ks], bfr, acc[mt]);
            }
            #pragma unroll
            for (int mt=0;mt<4;mt++)
                #pragma unroll
                for (int r=0;r<4;r++) {
                    float v = acc[mt][r]*INV_T;
                    int u = mt*4+r;
                    float nm = fmaxf(m16[u], v);
                    s16[u] = s16[u]*__expf(m16[u]-nm) + __expf(v-nm);
                    m16[u] = nm;
                }
        }
        #pragma unroll
        for (int u=0;u<16;u++) {
            #pragma unroll
            for (int o=1;o<16;o<<=1) {
                float om = __shfl_xor(m16[u],o), os = __shfl_xor(s16[u],o);
                float nm = fmaxf(m16[u],om);
                s16[u] = s16[u]*__expf(m16[u]-nm) + os*__expf(om-nm);
                m16[u] = nm;
            }
        }
        if (lo16 == 0) {
            #pragma unroll
            for (int u=0;u<16;u++) {
                int row = (u>>2)*16 + quad*4 + (u&3);
                redm[wave][row] = m16[u]; reds[wave][row] = s16[u];
            }
        }
        __syncthreads();
        if (tid < 64) {
            float m = redm[0][tid], s = reds[0][tid];
            for (int w=1;w<4;w++) {
                float om = redm[w][tid], os = reds[w][tid];
                float nm = fmaxf(m,om);
                s = s*__expf(m-nm) + os*__expf(om-nm);
                m = nm;
            }
            W[WS_PM + mu*8192 + ch*64 + tid] = m;
            W[WS_PS + mu*8192 + ch*64 + tid] = s;
        }
    } else {
        // ================= smat =================
        int i = bid - 2304;
        sa0[tid] = W[WS_CN + i*256 + tid];
        sa1[tid] = W[WS_RN + i*256 + tid];
        __syncthreads();
        const float* B0 = W + WS_RN;
        const float* B1v = W + WS_RAN;
        float av0 = sa0[tid], av1 = sa1[tid];
        for (int jj = 0; jj < 64; jj++) {
            float v0 = av0 * B0[jj*256 + tid];
            float v1 = av1 * B1v[jj*256 + tid];
            for (int o=1;o<64;o<<=1){ v0 += __shfl_xor(v0,o); v1 += __shfl_xor(v1,o); }
            if (lane==0){ part[0][jj][wave]=v0; part[1][jj][wave]=v1; }
        }
        __syncthreads();
        if (tid < 128) {
            int mat = tid>>6, jj = tid&63;
            float s = part[mat][jj][0]+part[mat][jj][1]+part[mat][jj][2]+part[mat][jj][3];
            W[(mat? WS_S2 : WS_S0) + i*64 + jj] = G3c * s;
        }
    }
}

// ---------------------------------------------------------------------------
// Final: all cross-entropies -> d_out[7]
// ---------------------------------------------------------------------------
__global__ __launch_bounds__(256) void final_kernel(
    const int* __restrict__ labels, float* __restrict__ W, float* __restrict__ out)
{
    int tid = threadIdx.x;
    __shared__ float mats[3][64][65];
    __shared__ float mmL[2][4][64], ssL[2][4][64];
    __shared__ float cearr[6][64];
    __shared__ float cemoco[128];

    for (int idx = tid; idx < 3*4096; idx += 256) {
        int t = idx >> 12, rem = idx & 4095;
        const float* src = W + (t==0 ? WS_SIM : (t==1 ? WS_S0 : WS_S2));
        mats[t][rem>>6][rem&63] = src[rem];
    }

    {
        int g = tid >> 6, r = tid & 63;
        for (int mu=0; mu<2; mu++) {
            float m = -1e30f, s = 0.f;
            for (int k=0; k<32; k++) {
                int ch = g*32 + k;
                float om = W[WS_PM + mu*8192 + ch*64 + r];
                float os = W[WS_PS + mu*8192 + ch*64 + r];
                float nm = fmaxf(m, om);
                s = s*__expf(m-nm) + os*__expf(om-nm);
                m = nm;
            }
            mmL[mu][g][r] = m; ssL[mu][g][r] = s;
        }
    }
    __syncthreads();

    if (tid < 128) {
        int mu = tid>>6, r = tid&63;
        float m = mmL[mu][0][r], s = ssL[mu][0][r];
        for (int g=1; g<4; g++) {
            float om = mmL[mu][g][r], os = ssL[mu][g][r];
            float nm = fmaxf(m, om);
            s = s*__expf(m-nm) + os*__expf(om-nm);
            m = nm;
        }
        const float* AT = W + (mu ? WS_RNT : WS_CNT);
        const float* BT = W + (mu ? WS_CANT : WS_RANT);
        float dot = 0.f;
        for (int c=0; c<256; c++) dot += AT[c*64 + r]*BT[c*64 + r];
        float v0 = dot*INV_T;
        float nm = fmaxf(m, v0);
        float S = s*__expf(m-nm) + __expf(v0-nm);
        cemoco[tid] = nm + __logf(S) - v0;
    }

    for (int pass=0; pass<2; pass++) {
        int cfg = pass*4 + (tid>>6);
        int row = tid&63;
        if (cfg < 6) {
            int mi; float scale; int colMajor;
            if (cfg==0){ mi=0; scale=G3c; colMajor=1; }
            else if (cfg==1){ mi=0; scale=G3c; colMajor=0; }
            else if (cfg==2){ mi=1; scale=1.f; colMajor=0; }
            else if (cfg==3){ mi=1; scale=1.f; colMajor=1; }
            else if (cfg==4){ mi=2; scale=1.f; colMajor=0; }
            else            { mi=2; scale=1.f; colMajor=1; }
            float mx = -1e30f;
            for (int x=0;x<64;x++) {
                float v = (colMajor? mats[mi][x][row] : mats[mi][row][x])*scale;
                mx = fmaxf(mx, v);
            }
            float se = 0.f;
            for (int x=0;x<64;x++) {
                float v = (colMajor? mats[mi][x][row] : mats[mi][row][x])*scale;
                se += __expf(v-mx);
            }
            int lbl = labels[row];
            float diag = (colMajor? mats[mi][lbl][row] : mats[mi][row][lbl])*scale;
            cearr[cfg][row] = mx + __logf(se) - diag;
        }
    }
    __syncthreads();

    if (tid < 7) {
        float r;
        if (tid == 4) {
            float s0=0.f, s1=0.f;
            for (int k=0;k<64;k++){ s0 += cemoco[k]; s1 += cemoco[64+k]; }
            r = (s0/64.f + s1/64.f)*0.5f;
        } else {
            int cfg = (tid < 4) ? tid : tid - 1;
            float s = 0.f;
            for (int k=0;k<64;k++) s += cearr[cfg][k];
            r = s/64.f;
        }
        out[tid] = r;
    }
}

// ---------------------------------------------------------------------------
extern "C" void kernel_launch(void* const* d_in, const int* in_sizes, int n_in,
                              void* d_out, int out_size, void* d_ws, size_t ws_size,
                              hipStream_t stream)
{
    const float* cnn   = (const float*)d_in[0];
    const float* rnn   = (const float*)d_in[1];
    const float* img   = (const float*)d_in[2];
    const float* wemb  = (const float*)d_in[3];
    const float* cnnA  = (const float*)d_in[4];
    const float* rnnA  = (const float*)d_in[5];
    const float* queue   = (const float*)d_in[6];
    const float* queueIm = (const float*)d_in[7];
    const int*   labels  = (const int*)d_in[9];
    float* W   = (float*)d_ws;
    float* out = (float*)d_out;

    prep_kernel<<<2048, 256, 0, stream>>>(cnn, rnn, img, wemb, cnnA, rnnA, W);
    attn_moco_kernel<<<2368, 256, 0, stream>>>(queue, queueIm, W);
    final_kernel<<<1, 256, 0, stream>>>(labels, W, out);
}

// Round 6
// 272.452 us; speedup vs baseline: 1.3511x; 1.3511x over previous
//
#include <hip/hip_runtime.h>
#include <hip/hip_bf16.h>
#include <math.h>

#define BB   64
#define TT   32
#define CC   256
#define KK   16384
#define G1c  4.0f
#define G2c  5.0f
#define G3c  10.0f
#define INV_T 20.0f
#define EPSF 1e-8f

// Workspace layout (floats)
#define WS_SIM 0
#define WS_S0  4096
#define WS_S2  8192
#define WS_CN  12288
#define WS_RN  28672
#define WS_CAN 45056
#define WS_RAN 61440
#define WS_QN  77824
#define WS_PM  79872                 // [2][128 ch][64 row]
#define WS_PS  (WS_PM + 16384)
#define WS_CNT  (WS_PS + 16384)      // [256][64] transposed codes
#define WS_RNT  (WS_CNT + 16384)
#define WS_CANT (WS_RNT + 16384)
#define WS_RANT (WS_CANT + 16384)
#define WS_F32_TOTAL (WS_RANT + 16384)

// bf16 arrays (shorts), after the f32 section
#define CTXT_ELEMS (64*320*256)    // ctxT[j][s(320)][c]
#define CTXC_ELEMS (64*256*320)    // ctxC[j][c][s(320)]
#define WQ_ELEMS   (64*32*256)     // wq[i][t][c]
#define CNRN_OFF   (CTXT_ELEMS + CTXC_ELEMS + WQ_ELEMS)  // [2][64][256]

#define SC_STR 260   // ctx_sc row stride (shorts): 130 dw ≡ 2 mod 4 -> conflict-free

typedef __attribute__((ext_vector_type(8))) short short8;
typedef __attribute__((ext_vector_type(4))) short short4v;
typedef __attribute__((ext_vector_type(4))) float float4v;

__device__ __forceinline__ float4v mfma_bf16(short8 a, short8 b, float4v c) {
    return __builtin_amdgcn_mfma_f32_16x16x32_bf16(a, b, c, 0, 0, 0);
}

__device__ __forceinline__ short f2bf(float f) {
    union { float f; unsigned u; } x; x.f = f;
    unsigned r = x.u + 0x7FFFu + ((x.u >> 16) & 1u);
    return (short)(r >> 16);
}

// LDS 8-short load as 2 x b64 (rows 8B-aligned)
__device__ __forceinline__ short8 ld8(const short* p) {
    short4v lo = *(const short4v*)p;
    short4v hi = *(const short4v*)(p + 4);
    short8 r = {lo[0],lo[1],lo[2],lo[3],hi[0],hi[1],hi[2],hi[3]};
    return r;
}

// ---------------------------------------------------------------------------
// Prep. grid: [0,256) codes | [256,320) qn | [320,1600) ctxT+ctxC | [1600,1664) wq
// ---------------------------------------------------------------------------
__global__ __launch_bounds__(256) void prep_kernel(
    const float* __restrict__ cnn, const float* __restrict__ rnn,
    const float* __restrict__ img, const float* __restrict__ wemb,
    const float* __restrict__ cnnA, const float* __restrict__ rnnA,
    float* __restrict__ W)
{
    int bid = blockIdx.x, tid = threadIdx.x;
    short* B16 = (short*)(W + WS_F32_TOTAL);
    short* ctxT = B16;
    short* ctxC = B16 + CTXT_ELEMS;
    short* wq   = B16 + CTXT_ELEMS + CTXC_ELEMS;
    short* cnrn = B16 + CNRN_OFF;

    if (bid < 256) {
        int mat = bid >> 6, row = bid & 63;
        const float* src = (mat==0)? cnn : (mat==1)? rnn : (mat==2)? cnnA : rnnA;
        float* dst  = W + ((mat==0)? WS_CN  : (mat==1)? WS_RN  : (mat==2)? WS_CAN  : WS_RAN);
        float* dstT = W + ((mat==0)? WS_CNT : (mat==1)? WS_RNT : (mat==2)? WS_CANT : WS_RANT);
        float v = src[row*256 + tid];
        float ss = v*v;
        for (int o=1;o<64;o<<=1) ss += __shfl_xor(ss,o);
        __shared__ float sc[4];
        if ((tid&63)==0) sc[tid>>6] = ss;
        __syncthreads();
        float tot = sc[0]+sc[1]+sc[2]+sc[3];
        float inv = 1.0f / fmaxf(sqrtf(tot), EPSF);
        float nv = v*inv;
        dst[row*256+tid] = nv;
        dstT[tid*64+row] = nv;
        if (mat < 2) cnrn[(mat*64+row)*256 + tid] = f2bf(nv);
    } else if (bid < 320) {
        int i = bid - 256;
        int t = tid >> 3, k = tid & 7;
        const float* wp = wemb + (i*32 + t)*256 + k*32;
        float ss = 0.f;
        for (int c=0;c<32;c++){ float v = wp[c]; ss += v*v; }
        ss += __shfl_xor(ss,1); ss += __shfl_xor(ss,2); ss += __shfl_xor(ss,4);
        if (k==0) W[WS_QN + i*32 + t] = sqrtf(ss);
    } else if (bid < 1600) {
        // one (j, 16-s-row) tile: emit BOTH ctxT[j][s][c] and ctxC[j][c][s]
        int b3 = bid - 320; int j = b3 / 20, mt = b3 % 20, s0 = mt*16;
        __shared__ float tile[16*257];
        for (int idx = tid; idx < 4096; idx += 256) {
            int c = idx >> 4, sl = idx & 15, s = s0 + sl;
            float v = (s < 289) ? img[((size_t)(j*256 + c))*289 + s] : 0.0f;
            tile[sl*257 + c] = v;
        }
        __syncthreads();
        for (int idx = tid; idx < 4096; idx += 256) {
            int orr = idx >> 8, c = idx & 255;
            ctxT[((size_t)(j*320 + s0 + orr))*256 + c] = f2bf(tile[orr*257 + c]);
        }
        {
            int c = tid;
            short tmp[16];
            #pragma unroll
            for (int sl = 0; sl < 16; sl++) tmp[sl] = f2bf(tile[sl*257 + c]);
            short* dstc = ctxC + ((size_t)(j*256 + c))*320 + s0;
            #pragma unroll
            for (int k2 = 0; k2 < 4; k2++) {
                short4v w = { tmp[k2*4], tmp[k2*4+1], tmp[k2*4+2], tmp[k2*4+3] };
                *(short4v*)(dstc + k2*4) = w;
            }
        }
    } else {
        for (int idx = (bid-1600)*256 + tid; idx < WQ_ELEMS; idx += 64*256) {
            wq[idx] = f2bf(wemb[idx]);
        }
    }
}

// ---------------------------------------------------------------------------
// Fused attn + moco + smat.
// bid < 2048: attention (j = bid>>5, i-pair = bid&31)
// bid in [2048,2304): moco MFMA (mu x 128 chunks of 128 cols)
// bid in [2304,2368): smat
// launch_bounds (256,2): cap 256 VGPRs -> NO SPILLS (R5 used ,3 -> 95 MB of
// scratch spill traffic; that was the regression).
// ---------------------------------------------------------------------------
__global__ __launch_bounds__(256, 2) void attn_moco_kernel(
    const float* __restrict__ queue, const float* __restrict__ queueIm,
    float* __restrict__ W)
{
    __shared__ short ctx_sc[32*SC_STR];            // 16640 B
    __shared__ short eTile[2][2][32][36];          // 9216 B (double-buffered)
    __shared__ float Dp[4][32], Np[4][32];
    __shared__ float wn2P[4][2][2][16];
    __shared__ float redm[4][64], reds[4][64];     // moco
    __shared__ float sa0[256], sa1[256];           // smat
    __shared__ float part[2][64][4];

    int bid = blockIdx.x, tid = threadIdx.x;
    int lane = tid & 63, wave = tid >> 6;
    int lo16 = lane & 15, quad = lane >> 4;

    const short* B16 = (const short*)(W + WS_F32_TOTAL);

    if (bid < 2048) {
        // ================= attention =================
        const short* ctxT = B16;
        const short* ctxC = B16 + CTXT_ELEMS;
        const short* wq   = B16 + CTXT_ELEMS + CTXC_ELEMS;

        int j = bid >> 5, ip = bid & 31;
        int i_l = wave >> 1, mt = wave & 1;     // wave -> (i_local, s-Mtile)
        int i_g = ip*2 + i_l;

        // wq fragments for this wave's i, BOTH t-halves (in VGPRs)
        short8 bq[2][8];
        {
            const short* p = wq + i_g*8192;
            #pragma unroll
            for (int nt2=0;nt2<2;nt2++)
                #pragma unroll
                for (int kk=0;kk<8;kk++)
                    bq[nt2][kk] = *(const short8*)(p + (nt2*16+lo16)*256 + kk*32 + quad*8);
        }

        float4v wacc[4][4];
        #pragma unroll
        for (int cm=0;cm<4;cm++)
            #pragma unroll
            for (int cb=0;cb<4;cb++) wacc[cm][cb] = (float4v){0.f,0.f,0.f,0.f};
        float D0=0.f, D1=0.f, N0=0.f, N1=0.f;

        const short* ctxTj = ctxT + (size_t)j * (320*256);
        const short* ctxCj = ctxC + (size_t)j * (256*320);
        int s_row = tid >> 3, c0s = (tid & 7)*32;
        int srow_base = mt*16 + quad*4;         // this lane's s rows (+r) in tile

        // prefetch tile 0 of ctx_sc
        short8 pf[4];
        {
            const short* g = ctxTj + s_row*256 + c0s;
            #pragma unroll
            for (int m=0;m<4;m++) pf[m] = *(const short8*)(g + m*8);
        }

        for (int tile = 0; tile < 10; tile++) {
            // stage prefetched regs -> ctx_sc (b64 writes)
            {
                short* d = ctx_sc + s_row*SC_STR + c0s;
                #pragma unroll
                for (int k=0;k<8;k++) {
                    short4v w = { pf[k>>1][(k&1)*4+0], pf[k>>1][(k&1)*4+1],
                                  pf[k>>1][(k&1)*4+2], pf[k>>1][(k&1)*4+3] };
                    *(short4v*)(d + k*4) = w;
                }
            }
            __syncthreads();                     // B1: stores visible
            // prefetch next ctx_sc tile
            if (tile < 9) {
                const short* g = ctxTj + ((tile+1)*32 + s_row)*256 + c0s;
                #pragma unroll
                for (int m=0;m<4;m++) pf[m] = *(const short8*)(g + m*8);
            }
            // wC A-frags from global ctxC (independent -> issued early)
            short8 wa[4];
            #pragma unroll
            for (int cm=0;cm<4;cm++)
                wa[cm] = *(const short8*)(ctxCj + (size_t)((wave*4+cm)*16+lo16)*320 + tile*32 + quad*8);

            // scores MFMA: this wave's s-Mtile, all 32 t
            float4v a0 = {0.f,0.f,0.f,0.f}, a1 = {0.f,0.f,0.f,0.f};
            {
                const short* ar = ctx_sc + (mt*16 + lo16)*SC_STR + quad*8;
                #pragma unroll
                for (int kk=0;kk<8;kk++) {
                    short8 a = ld8(ar + kk*32);
                    a0 = mfma_bf16(a, bq[0][kk], a0);
                    a1 = mfma_bf16(a, bq[1][kk], a1);
                }
            }
            // in-register softmax over t per s-row; e -> eTile; D/N accum
            int eb = tile & 1;
            #pragma unroll
            for (int r=0;r<4;r++) {
                float mx = fmaxf(a0[r], a1[r]);
                mx = fmaxf(mx, __shfl_xor(mx,1));
                mx = fmaxf(mx, __shfl_xor(mx,2));
                mx = fmaxf(mx, __shfl_xor(mx,4));
                mx = fmaxf(mx, __shfl_xor(mx,8));
                float e0 = __expf(a0[r]-mx), e1 = __expf(a1[r]-mx);
                float z = e0 + e1;
                z += __shfl_xor(z,1); z += __shfl_xor(z,2);
                z += __shfl_xor(z,4); z += __shfl_xor(z,8);
                float rinv = 1.0f/z;
                int s_local = srow_base + r;
                int sg = tile*32 + s_local;
                float ev0 = 0.f, ev1 = 0.f;
                if (sg < 289) {
                    ev0 = __expf(G1c*e0*rinv);
                    ev1 = __expf(G1c*e1*rinv);
                    D0 += ev0; N0 += ev0*a0[r];
                    D1 += ev1; N1 += ev1*a1[r];
                }
                eTile[eb][i_l][lo16][s_local]    = f2bf(ev0);
                eTile[eb][i_l][16+lo16][s_local] = f2bf(ev1);
            }
            __syncthreads();                     // B2: eTile visible, ctx_sc reads done
            // wC MFMA: K=32 (one step), 4 Mtiles x 4 combos, B from eTile
            {
                short8 bf0 = ld8(&eTile[eb][0][lo16][quad*8]);
                short8 bf1 = ld8(&eTile[eb][0][16+lo16][quad*8]);
                short8 bf2 = ld8(&eTile[eb][1][lo16][quad*8]);
                short8 bf3 = ld8(&eTile[eb][1][16+lo16][quad*8]);
                #pragma unroll
                for (int cm=0;cm<4;cm++) {
                    wacc[cm][0] = mfma_bf16(wa[cm], bf0, wacc[cm][0]);
                    wacc[cm][1] = mfma_bf16(wa[cm], bf1, wacc[cm][1]);
                    wacc[cm][2] = mfma_bf16(wa[cm], bf2, wacc[cm][2]);
                    wacc[cm][3] = mfma_bf16(wa[cm], bf3, wacc[cm][3]);
                }
            }
            // no barrier here: next tile writes the other eTile buffer
        }

        // D/N reduce over quads, publish per wave
        D0 += __shfl_xor(D0,16); D0 += __shfl_xor(D0,32);
        D1 += __shfl_xor(D1,16); D1 += __shfl_xor(D1,32);
        N0 += __shfl_xor(N0,16); N0 += __shfl_xor(N0,32);
        N1 += __shfl_xor(N1,16); N1 += __shfl_xor(N1,32);
        if (lane < 16) {
            Dp[wave][lane] = D0; Dp[wave][16+lane] = D1;
            Np[wave][lane] = N0; Np[wave][16+lane] = N1;
        }
        // wn2 partials from wacc
        #pragma unroll
        for (int cb=0;cb<4;cb++) {
            float ss = 0.f;
            #pragma unroll
            for (int cm=0;cm<4;cm++)
                #pragma unroll
                for (int r=0;r<4;r++){ float v = wacc[cm][cb][r]; ss += v*v; }
            ss += __shfl_xor(ss,16);
            ss += __shfl_xor(ss,32);
            if (quad==0) wn2P[wave][cb>>1][cb&1][lo16] = ss;
        }
        __syncthreads();

        // epilogue
        if (tid < 64) {
            int i_f = tid >> 5, t = tid & 31;
            int nt2 = t >> 4, lo = t & 15;
            float w2 = wn2P[0][i_f][nt2][lo] + wn2P[1][i_f][nt2][lo]
                     + wn2P[2][i_f][nt2][lo] + wn2P[3][i_f][nt2][lo];
            float D = Dp[i_f*2][t] + Dp[i_f*2+1][t];
            float N = Np[i_f*2][t] + Np[i_f*2+1][t];
            int i_gf = ip*2 + i_f;
            float qv = W[WS_QN + i_gf*32 + t];
            float numS = N/D;
            float wnS = sqrtf(w2)/D;
            float v = G2c * (numS / fmaxf(qv*wnS, EPSF));
            float mx = v;
            for (int o=1;o<32;o<<=1) mx = fmaxf(mx, __shfl_xor(mx,o));
            float e = __expf(v-mx);
            for (int o=1;o<32;o<<=1) e += __shfl_xor(e,o);
            if (t==0) W[WS_SIM + i_gf*64 + j] = mx + __logf(e);
        }
    } else if (bid < 2304) {
        // ================= moco =================
        int bid2 = bid - 2048;
        int mu = bid2 >> 7, ch = bid2 & 127;
        const float* Q = mu ? queueIm : queue;
        const short* Abf = B16 + CNRN_OFF + mu*16384;

        short8 afr[4][8];
        #pragma unroll
        for (int mt=0;mt<4;mt++)
            #pragma unroll
            for (int kk=0;kk<8;kk++)
                afr[mt][kk] = *(const short8*)(Abf + (mt*16+lo16)*256 + kk*32 + quad*8);

        float m16[16], s16[16];
        #pragma unroll
        for (int u=0;u<16;u++){ m16[u] = -1e30f; s16[u] = 0.f; }

        for (int t4 = 0; t4 < 2; t4++) {
            int colb = ch*128 + (wave*2 + t4)*16;
            float4v acc[4];
            #pragma unroll
            for (int mt=0;mt<4;mt++) acc[mt] = (float4v){0.f,0.f,0.f,0.f};
            for (int ks = 0; ks < 8; ks++) {
                short8 bfr;
                #pragma unroll
                for (int jj=0;jj<8;jj++) {
                    float bv = Q[(size_t)(ks*32 + quad*8 + jj)*KK + colb + lo16];
                    bfr[jj] = f2bf(bv);
                }
                #pragma unroll
                for (int mt=0;mt<4;mt++) acc[mt] = mfma_bf16(afr[mt][ks], bfr, acc[mt]);
            }
            #pragma unroll
            for (int mt=0;mt<4;mt++)
                #pragma unroll
                for (int r=0;r<4;r++) {
                    float v = acc[mt][r]*INV_T;
                    int u = mt*4+r;
                    float nm = fmaxf(m16[u], v);
                    s16[u] = s16[u]*__expf(m16[u]-nm) + __expf(v-nm);
                    m16[u] = nm;
                }
        }
        #pragma unroll
        for (int u=0;u<16;u++) {
            #pragma unroll
            for (int o=1;o<16;o<<=1) {
                float om = __shfl_xor(m16[u],o), os = __shfl_xor(s16[u],o);
                float nm = fmaxf(m16[u],om);
                s16[u] = s16[u]*__expf(m16[u]-nm) + os*__expf(om-nm);
                m16[u] = nm;
            }
        }
        if (lo16 == 0) {
            #pragma unroll
            for (int u=0;u<16;u++) {
                int row = (u>>2)*16 + quad*4 + (u&3);
                redm[wave][row] = m16[u]; reds[wave][row] = s16[u];
            }
        }
        __syncthreads();
        if (tid < 64) {
            float m = redm[0][tid], s = reds[0][tid];
            for (int w=1;w<4;w++) {
                float om = redm[w][tid], os = reds[w][tid];
                float nm = fmaxf(m,om);
                s = s*__expf(m-nm) + os*__expf(om-nm);
                m = nm;
            }
            W[WS_PM + mu*8192 + ch*64 + tid] = m;
            W[WS_PS + mu*8192 + ch*64 + tid] = s;
        }
    } else {
        // ================= smat =================
        int i = bid - 2304;
        sa0[tid] = W[WS_CN + i*256 + tid];
        sa1[tid] = W[WS_RN + i*256 + tid];
        __syncthreads();
        const float* B0 = W + WS_RN;
        const float* B1v = W + WS_RAN;
        float av0 = sa0[tid], av1 = sa1[tid];
        for (int jj = 0; jj < 64; jj++) {
            float v0 = av0 * B0[jj*256 + tid];
            float v1 = av1 * B1v[jj*256 + tid];
            for (int o=1;o<64;o<<=1){ v0 += __shfl_xor(v0,o); v1 += __shfl_xor(v1,o); }
            if (lane==0){ part[0][jj][wave]=v0; part[1][jj][wave]=v1; }
        }
        __syncthreads();
        if (tid < 128) {
            int mat = tid>>6, jj = tid&63;
            float s = part[mat][jj][0]+part[mat][jj][1]+part[mat][jj][2]+part[mat][jj][3];
            W[(mat? WS_S2 : WS_S0) + i*64 + jj] = G3c * s;
        }
    }
}

// ---------------------------------------------------------------------------
// Final: all cross-entropies -> d_out[7]
// ---------------------------------------------------------------------------
__global__ __launch_bounds__(256) void final_kernel(
    const int* __restrict__ labels, float* __restrict__ W, float* __restrict__ out)
{
    int tid = threadIdx.x;
    __shared__ float mats[3][64][65];
    __shared__ float mmL[2][4][64], ssL[2][4][64];
    __shared__ float cearr[6][64];
    __shared__ float cemoco[128];

    for (int idx = tid; idx < 3*4096; idx += 256) {
        int t = idx >> 12, rem = idx & 4095;
        const float* src = W + (t==0 ? WS_SIM : (t==1 ? WS_S0 : WS_S2));
        mats[t][rem>>6][rem&63] = src[rem];
    }

    {
        int g = tid >> 6, r = tid & 63;
        for (int mu=0; mu<2; mu++) {
            float m = -1e30f, s = 0.f;
            for (int k=0; k<32; k++) {
                int ch = g*32 + k;
                float om = W[WS_PM + mu*8192 + ch*64 + r];
                float os = W[WS_PS + mu*8192 + ch*64 + r];
                float nm = fmaxf(m, om);
                s = s*__expf(m-nm) + os*__expf(om-nm);
                m = nm;
            }
            mmL[mu][g][r] = m; ssL[mu][g][r] = s;
        }
    }
    __syncthreads();

    if (tid < 128) {
        int mu = tid>>6, r = tid&63;
        float m = mmL[mu][0][r], s = ssL[mu][0][r];
        for (int g=1; g<4; g++) {
            float om = mmL[mu][g][r], os = ssL[mu][g][r];
            float nm = fmaxf(m, om);
            s = s*__expf(m-nm) + os*__expf(om-nm);
            m = nm;
        }
        const float* AT = W + (mu ? WS_RNT : WS_CNT);
        const float* BT = W + (mu ? WS_CANT : WS_RANT);
        float dot = 0.f;
        for (int c=0; c<256; c++) dot += AT[c*64 + r]*BT[c*64 + r];
        float v0 = dot*INV_T;
        float nm = fmaxf(m, v0);
        float S = s*__expf(m-nm) + __expf(v0-nm);
        cemoco[tid] = nm + __logf(S) - v0;
    }

    for (int pass=0; pass<2; pass++) {
        int cfg = pass*4 + (tid>>6);
        int row = tid&63;
        if (cfg < 6) {
            int mi; float scale; int colMajor;
            if (cfg==0){ mi=0; scale=G3c; colMajor=1; }
            else if (cfg==1){ mi=0; scale=G3c; colMajor=0; }
            else if (cfg==2){ mi=1; scale=1.f; colMajor=0; }
            else if (cfg==3){ mi=1; scale=1.f; colMajor=1; }
            else if (cfg==4){ mi=2; scale=1.f; colMajor=0; }
            else            { mi=2; scale=1.f; colMajor=1; }
            float mx = -1e30f;
            for (int x=0;x<64;x++) {
                float v = (colMajor? mats[mi][x][row] : mats[mi][row][x])*scale;
                mx = fmaxf(mx, v);
            }
            float se = 0.f;
            for (int x=0;x<64;x++) {
                float v = (colMajor? mats[mi][x][row] : mats[mi][row][x])*scale;
                se += __expf(v-mx);
            }
            int lbl = labels[row];
            float diag = (colMajor? mats[mi][lbl][row] : mats[mi][row][lbl])*scale;
            cearr[cfg][row] = mx + __logf(se) - diag;
        }
    }
    __syncthreads();

    if (tid < 7) {
        float r;
        if (tid == 4) {
            float s0=0.f, s1=0.f;
            for (int k=0;k<64;k++){ s0 += cemoco[k]; s1 += cemoco[64+k]; }
            r = (s0/64.f + s1/64.f)*0.5f;
        } else {
            int cfg = (tid < 4) ? tid : tid - 1;
            float s = 0.f;
            for (int k=0;k<64;k++) s += cearr[cfg][k];
            r = s/64.f;
        }
        out[tid] = r;
    }
}

// ---------------------------------------------------------------------------
extern "C" void kernel_launch(void* const* d_in, const int* in_sizes, int n_in,
                              void* d_out, int out_size, void* d_ws, size_t ws_size,
                              hipStream_t stream)
{
    const float* cnn   = (const float*)d_in[0];
    const float* rnn   = (const float*)d_in[1];
    const float* img   = (const float*)d_in[2];
    const float* wemb  = (const float*)d_in[3];
    const float* cnnA  = (const float*)d_in[4];
    const float* rnnA  = (const float*)d_in[5];
    const float* queue   = (const float*)d_in[6];
    const float* queueIm = (const float*)d_in[7];
    const int*   labels  = (const int*)d_in[9];
    float* W   = (float*)d_ws;
    float* out = (float*)d_out;

    prep_kernel<<<1664, 256, 0, stream>>>(cnn, rnn, img, wemb, cnnA, rnnA, W);
    attn_moco_kernel<<<2368, 256, 0, stream>>>(queue, queueIm, W);
    final_kernel<<<1, 256, 0, stream>>>(labels, W, out);
}

// Round 7
// 251.776 us; speedup vs baseline: 1.4620x; 1.0821x over previous
//
#include <hip/hip_runtime.h>
#include <hip/hip_bf16.h>
#include <math.h>

#define BB   64
#define TT   32
#define CC   256
#define KK   16384
#define G1c  4.0f
#define G2c  5.0f
#define G3c  10.0f
#define INV_T 20.0f
#define EPSF 1e-8f

// Workspace layout (floats)
#define WS_SIM 0
#define WS_S0  4096
#define WS_S2  8192
#define WS_CN  12288
#define WS_RN  28672
#define WS_CAN 45056
#define WS_RAN 61440
#define WS_QN  77824
#define WS_PM  79872                 // [2][128 ch][64 row]
#define WS_PS  (WS_PM + 16384)
#define WS_CNT  (WS_PS + 16384)      // [256][64] transposed codes
#define WS_RNT  (WS_CNT + 16384)
#define WS_CANT (WS_RNT + 16384)
#define WS_RANT (WS_CANT + 16384)
#define WS_F32_TOTAL (WS_RANT + 16384)

// bf16 arrays (shorts), after the f32 section
#define CTXT_ELEMS (64*320*256)    // ctxT[j][s(320)][c]
#define WQ_ELEMS   (64*32*256)     // wq[i][t][c]
#define WQ_OFF     CTXT_ELEMS
#define CNRN_OFF   (CTXT_ELEMS + WQ_ELEMS)   // [2][64][256]

#define SC_STR 260   // ctx_sc row stride (shorts): 130 dw ≡ 2 mod 4 -> conflict-free

typedef __attribute__((ext_vector_type(8))) short short8;
typedef __attribute__((ext_vector_type(4))) short short4v;
typedef __attribute__((ext_vector_type(4))) float float4v;

__device__ __forceinline__ float4v mfma_bf16(short8 a, short8 b, float4v c) {
    return __builtin_amdgcn_mfma_f32_16x16x32_bf16(a, b, c, 0, 0, 0);
}

__device__ __forceinline__ short f2bf(float f) {
    union { float f; unsigned u; } x; x.f = f;
    unsigned r = x.u + 0x7FFFu + ((x.u >> 16) & 1u);
    return (short)(r >> 16);
}

// LDS 8-short load as 2 x b64 (rows 8B-aligned)
__device__ __forceinline__ short8 ld8(const short* p) {
    short4v lo = *(const short4v*)p;
    short4v hi = *(const short4v*)(p + 4);
    short8 r = {lo[0],lo[1],lo[2],lo[3],hi[0],hi[1],hi[2],hi[3]};
    return r;
}

// ---------------------------------------------------------------------------
// Prep. grid: [0,256) codes | [256,320) qn | [320,1600) ctxT | [1600,1664) wq
// ---------------------------------------------------------------------------
__global__ __launch_bounds__(256) void prep_kernel(
    const float* __restrict__ cnn, const float* __restrict__ rnn,
    const float* __restrict__ img, const float* __restrict__ wemb,
    const float* __restrict__ cnnA, const float* __restrict__ rnnA,
    float* __restrict__ W)
{
    int bid = blockIdx.x, tid = threadIdx.x;
    short* B16 = (short*)(W + WS_F32_TOTAL);
    short* ctxT = B16;
    short* wq   = B16 + WQ_OFF;
    short* cnrn = B16 + CNRN_OFF;

    if (bid < 256) {
        int mat = bid >> 6, row = bid & 63;
        const float* src = (mat==0)? cnn : (mat==1)? rnn : (mat==2)? cnnA : rnnA;
        float* dst  = W + ((mat==0)? WS_CN  : (mat==1)? WS_RN  : (mat==2)? WS_CAN  : WS_RAN);
        float* dstT = W + ((mat==0)? WS_CNT : (mat==1)? WS_RNT : (mat==2)? WS_CANT : WS_RANT);
        float v = src[row*256 + tid];
        float ss = v*v;
        for (int o=1;o<64;o<<=1) ss += __shfl_xor(ss,o);
        __shared__ float sc[4];
        if ((tid&63)==0) sc[tid>>6] = ss;
        __syncthreads();
        float tot = sc[0]+sc[1]+sc[2]+sc[3];
        float inv = 1.0f / fmaxf(sqrtf(tot), EPSF);
        float nv = v*inv;
        dst[row*256+tid] = nv;
        dstT[tid*64+row] = nv;
        if (mat < 2) cnrn[(mat*64+row)*256 + tid] = f2bf(nv);
    } else if (bid < 320) {
        int i = bid - 256;
        int t = tid >> 3, k = tid & 7;
        const float* wp = wemb + (i*32 + t)*256 + k*32;
        float ss = 0.f;
        for (int c=0;c<32;c++){ float v = wp[c]; ss += v*v; }
        ss += __shfl_xor(ss,1); ss += __shfl_xor(ss,2); ss += __shfl_xor(ss,4);
        if (k==0) W[WS_QN + i*32 + t] = sqrtf(ss);
    } else if (bid < 1600) {
        // ctxT[j][s][c] bf16, s padded to 320 (zeros for s>=289)
        int b3 = bid - 320; int j = b3 / 20, mt = b3 % 20, s0 = mt*16;
        __shared__ float tile[16*257];
        for (int idx = tid; idx < 4096; idx += 256) {
            int c = idx >> 4, sl = idx & 15, s = s0 + sl;
            float v = (s < 289) ? img[((size_t)(j*256 + c))*289 + s] : 0.0f;
            tile[sl*257 + c] = v;
        }
        __syncthreads();
        for (int idx = tid; idx < 4096; idx += 256) {
            int orr = idx >> 8, c = idx & 255;
            ctxT[((size_t)(j*320 + s0 + orr))*256 + c] = f2bf(tile[orr*257 + c]);
        }
    } else {
        for (int idx = (bid-1600)*256 + tid; idx < WQ_ELEMS; idx += 64*256) {
            wq[idx] = f2bf(wemb[idx]);
        }
    }
}

// ---------------------------------------------------------------------------
// Fused moco + smat + attn. moco/smat FIRST so they overlap attn instead of
// running as a serial tail.
// bid < 256: moco MFMA (mu = bid>>7, 128-col chunks)
// bid in [256,320): smat
// bid >= 320: attention (abid = bid-320: j = abid>>5, i-pair = abid&31)
// launch_bounds (256,2): 256-VGPR cap -> no spills (R5 lesson).
// ---------------------------------------------------------------------------
__global__ __launch_bounds__(256, 2) void attn_moco_kernel(
    const float* __restrict__ queue, const float* __restrict__ queueIm,
    float* __restrict__ W)
{
    __shared__ short ctx_sc[32*SC_STR];            // 16640 B
    __shared__ short eTile[2][2][32][36];          // 9216 B (double-buffered)
    __shared__ float Dp[4][32], Np[4][32];
    __shared__ float wn2P[4][2][2][16];
    __shared__ float redm[4][64], reds[4][64];     // moco
    __shared__ float sa0[256], sa1[256];           // smat
    __shared__ float part[2][64][4];

    int bid = blockIdx.x, tid = threadIdx.x;
    int lane = tid & 63, wave = tid >> 6;
    int lo16 = lane & 15, quad = lane >> 4;

    const short* B16 = (const short*)(W + WS_F32_TOTAL);

    if (bid >= 320) {
        // ================= attention =================
        const short* ctxT = B16;
        const short* wq   = B16 + WQ_OFF;

        int abid = bid - 320;
        int j = abid >> 5, ip = abid & 31;
        int i_l = wave >> 1, mt = wave & 1;     // wave -> (i_local, s-Mtile)
        int i_g = ip*2 + i_l;

        // wq fragments for this wave's i, BOTH t-halves (in VGPRs)
        short8 bq[2][8];
        {
            const short* p = wq + i_g*8192;
            #pragma unroll
            for (int nt2=0;nt2<2;nt2++)
                #pragma unroll
                for (int kk=0;kk<8;kk++)
                    bq[nt2][kk] = *(const short8*)(p + (nt2*16+lo16)*256 + kk*32 + quad*8);
        }

        float4v wacc[4][4];
        #pragma unroll
        for (int cm=0;cm<4;cm++)
            #pragma unroll
            for (int cb=0;cb<4;cb++) wacc[cm][cb] = (float4v){0.f,0.f,0.f,0.f};
        float D0=0.f, D1=0.f, N0=0.f, N1=0.f;

        const short* ctxTj = ctxT + (size_t)j * (320*256);
        int s_row = tid >> 3, c0s = (tid & 7)*32;
        int srow_base = mt*16 + quad*4;         // this lane's s rows (+r) in tile

        // prefetch tile 0 of ctx_sc
        short8 pf[4];
        {
            const short* g = ctxTj + s_row*256 + c0s;
            #pragma unroll
            for (int m=0;m<4;m++) pf[m] = *(const short8*)(g + m*8);
        }

        for (int tile = 0; tile < 10; tile++) {
            // stage prefetched regs -> ctx_sc (b64 writes)
            {
                short* d = ctx_sc + s_row*SC_STR + c0s;
                #pragma unroll
                for (int k=0;k<8;k++) {
                    short4v w = { pf[k>>1][(k&1)*4+0], pf[k>>1][(k&1)*4+1],
                                  pf[k>>1][(k&1)*4+2], pf[k>>1][(k&1)*4+3] };
                    *(short4v*)(d + k*4) = w;
                }
            }
            __syncthreads();                     // B1: stores visible
            // prefetch next ctx_sc tile
            if (tile < 9) {
                const short* g = ctxTj + ((tile+1)*32 + s_row)*256 + c0s;
                #pragma unroll
                for (int m=0;m<4;m++) pf[m] = *(const short8*)(g + m*8);
            }

            // scores MFMA: this wave's s-Mtile, all 32 t
            float4v a0 = {0.f,0.f,0.f,0.f}, a1 = {0.f,0.f,0.f,0.f};
            {
                const short* ar = ctx_sc + (mt*16 + lo16)*SC_STR + quad*8;
                #pragma unroll
                for (int kk=0;kk<8;kk++) {
                    short8 a = ld8(ar + kk*32);
                    a0 = mfma_bf16(a, bq[0][kk], a0);
                    a1 = mfma_bf16(a, bq[1][kk], a1);
                }
            }

            // wC A-frags: transpose-gather from ctx_sc (u16 reads, 2-way max
            // bank aliasing = free). Replaces the 160 KB/block ctxC stream.
            short8 wa[4];
            #pragma unroll
            for (int cm=0;cm<4;cm++) {
                const short* col = ctx_sc + quad*8*SC_STR + wave*64 + cm*16 + lo16;
                short8 v;
                #pragma unroll
                for (int jj=0;jj<8;jj++) v[jj] = col[jj*SC_STR];
                wa[cm] = v;
            }

            // in-register softmax over t per s-row; e -> eTile; D/N accum
            int eb = tile & 1;
            #pragma unroll
            for (int r=0;r<4;r++) {
                float mx = fmaxf(a0[r], a1[r]);
                mx = fmaxf(mx, __shfl_xor(mx,1));
                mx = fmaxf(mx, __shfl_xor(mx,2));
                mx = fmaxf(mx, __shfl_xor(mx,4));
                mx = fmaxf(mx, __shfl_xor(mx,8));
                float e0 = __expf(a0[r]-mx), e1 = __expf(a1[r]-mx);
                float z = e0 + e1;
                z += __shfl_xor(z,1); z += __shfl_xor(z,2);
                z += __shfl_xor(z,4); z += __shfl_xor(z,8);
                float rinv = 1.0f/z;
                int s_local = srow_base + r;
                int sg = tile*32 + s_local;
                float ev0 = 0.f, ev1 = 0.f;
                if (sg < 289) {
                    ev0 = __expf(G1c*e0*rinv);
                    ev1 = __expf(G1c*e1*rinv);
                    D0 += ev0; N0 += ev0*a0[r];
                    D1 += ev1; N1 += ev1*a1[r];
                }
                eTile[eb][i_l][lo16][s_local]    = f2bf(ev0);
                eTile[eb][i_l][16+lo16][s_local] = f2bf(ev1);
            }
            __syncthreads();                     // B2: eTile visible, ctx_sc reads done
            // wC MFMA: K=32 (one step), 4 Mtiles x 4 combos, B from eTile
            {
                short8 bf0 = ld8(&eTile[eb][0][lo16][quad*8]);
                short8 bf1 = ld8(&eTile[eb][0][16+lo16][quad*8]);
                short8 bf2 = ld8(&eTile[eb][1][lo16][quad*8]);
                short8 bf3 = ld8(&eTile[eb][1][16+lo16][quad*8]);
                #pragma unroll
                for (int cm=0;cm<4;cm++) {
                    wacc[cm][0] = mfma_bf16(wa[cm], bf0, wacc[cm][0]);
                    wacc[cm][1] = mfma_bf16(wa[cm], bf1, wacc[cm][1]);
                    wacc[cm][2] = mfma_bf16(wa[cm], bf2, wacc[cm][2]);
                    wacc[cm][3] = mfma_bf16(wa[cm], bf3, wacc[cm][3]);
                }
            }
            // no barrier: next tile's stage is ordered by B2; eTile alternates
        }

        // D/N reduce over quads, publish per wave
        D0 += __shfl_xor(D0,16); D0 += __shfl_xor(D0,32);
        D1 += __shfl_xor(D1,16); D1 += __shfl_xor(D1,32);
        N0 += __shfl_xor(N0,16); N0 += __shfl_xor(N0,32);
        N1 += __shfl_xor(N1,16); N1 += __shfl_xor(N1,32);
        if (lane < 16) {
            Dp[wave][lane] = D0; Dp[wave][16+lane] = D1;
            Np[wave][lane] = N0; Np[wave][16+lane] = N1;
        }
        // wn2 partials from wacc
        #pragma unroll
        for (int cb=0;cb<4;cb++) {
            float ss = 0.f;
            #pragma unroll
            for (int cm=0;cm<4;cm++)
                #pragma unroll
                for (int r=0;r<4;r++){ float v = wacc[cm][cb][r]; ss += v*v; }
            ss += __shfl_xor(ss,16);
            ss += __shfl_xor(ss,32);
            if (quad==0) wn2P[wave][cb>>1][cb&1][lo16] = ss;
        }
        __syncthreads();

        // epilogue
        if (tid < 64) {
            int i_f = tid >> 5, t = tid & 31;
            int nt2 = t >> 4, lo = t & 15;
            float w2 = wn2P[0][i_f][nt2][lo] + wn2P[1][i_f][nt2][lo]
                     + wn2P[2][i_f][nt2][lo] + wn2P[3][i_f][nt2][lo];
            float D = Dp[i_f*2][t] + Dp[i_f*2+1][t];
            float N = Np[i_f*2][t] + Np[i_f*2+1][t];
            int i_gf = ip*2 + i_f;
            float qv = W[WS_QN + i_gf*32 + t];
            float numS = N/D;
            float wnS = sqrtf(w2)/D;
            float v = G2c * (numS / fmaxf(qv*wnS, EPSF));
            float mx = v;
            for (int o=1;o<32;o<<=1) mx = fmaxf(mx, __shfl_xor(mx,o));
            float e = __expf(v-mx);
            for (int o=1;o<32;o<<=1) e += __shfl_xor(e,o);
            if (t==0) W[WS_SIM + i_gf*64 + j] = mx + __logf(e);
        }
    } else if (bid < 256) {
        // ================= moco =================
        int mu = bid >> 7, ch = bid & 127;
        const float* Q = mu ? queueIm : queue;
        const short* Abf = B16 + CNRN_OFF + mu*16384;

        short8 afr[4][8];
        #pragma unroll
        for (int mt=0;mt<4;mt++)
            #pragma unroll
            for (int kk=0;kk<8;kk++)
                afr[mt][kk] = *(const short8*)(Abf + (mt*16+lo16)*256 + kk*32 + quad*8);

        float m16[16], s16[16];
        #pragma unroll
        for (int u=0;u<16;u++){ m16[u] = -1e30f; s16[u] = 0.f; }

        for (int t4 = 0; t4 < 2; t4++) {
            int colb = ch*128 + (wave*2 + t4)*16;
            float4v acc[4];
            #pragma unroll
            for (int mt=0;mt<4;mt++) acc[mt] = (float4v){0.f,0.f,0.f,0.f};
            for (int ks = 0; ks < 8; ks++) {
                short8 bfr;
                #pragma unroll
                for (int jj=0;jj<8;jj++) {
                    float bv = Q[(size_t)(ks*32 + quad*8 + jj)*KK + colb + lo16];
                    bfr[jj] = f2bf(bv);
                }
                #pragma unroll
                for (int mt=0;mt<4;mt++) acc[mt] = mfma_bf16(afr[mt][ks], bfr, acc[mt]);
            }
            #pragma unroll
            for (int mt=0;mt<4;mt++)
                #pragma unroll
                for (int r=0;r<4;r++) {
                    float v = acc[mt][r]*INV_T;
                    int u = mt*4+r;
                    float nm = fmaxf(m16[u], v);
                    s16[u] = s16[u]*__expf(m16[u]-nm) + __expf(v-nm);
                    m16[u] = nm;
                }
        }
        #pragma unroll
        for (int u=0;u<16;u++) {
            #pragma unroll
            for (int o=1;o<16;o<<=1) {
                float om = __shfl_xor(m16[u],o), os = __shfl_xor(s16[u],o);
                float nm = fmaxf(m16[u],om);
                s16[u] = s16[u]*__expf(m16[u]-nm) + os*__expf(om-nm);
                m16[u] = nm;
            }
        }
        if (lo16 == 0) {
            #pragma unroll
            for (int u=0;u<16;u++) {
                int row = (u>>2)*16 + quad*4 + (u&3);
                redm[wave][row] = m16[u]; reds[wave][row] = s16[u];
            }
        }
        __syncthreads();
        if (tid < 64) {
            float m = redm[0][tid], s = reds[0][tid];
            for (int w=1;w<4;w++) {
                float om = redm[w][tid], os = reds[w][tid];
                float nm = fmaxf(m,om);
                s = s*__expf(m-nm) + os*__expf(om-nm);
                m = nm;
            }
            W[WS_PM + mu*8192 + ch*64 + tid] = m;
            W[WS_PS + mu*8192 + ch*64 + tid] = s;
        }
    } else {
        // ================= smat =================
        int i = bid - 256;
        sa0[tid] = W[WS_CN + i*256 + tid];
        sa1[tid] = W[WS_RN + i*256 + tid];
        __syncthreads();
        const float* B0 = W + WS_RN;
        const float* B1v = W + WS_RAN;
        float av0 = sa0[tid], av1 = sa1[tid];
        for (int jj = 0; jj < 64; jj++) {
            float v0 = av0 * B0[jj*256 + tid];
            float v1 = av1 * B1v[jj*256 + tid];
            for (int o=1;o<64;o<<=1){ v0 += __shfl_xor(v0,o); v1 += __shfl_xor(v1,o); }
            if (lane==0){ part[0][jj][wave]=v0; part[1][jj][wave]=v1; }
        }
        __syncthreads();
        if (tid < 128) {
            int mat = tid>>6, jj = tid&63;
            float s = part[mat][jj][0]+part[mat][jj][1]+part[mat][jj][2]+part[mat][jj][3];
            W[(mat? WS_S2 : WS_S0) + i*64 + jj] = G3c * s;
        }
    }
}

// ---------------------------------------------------------------------------
// Final: all cross-entropies -> d_out[7]
// ---------------------------------------------------------------------------
__global__ __launch_bounds__(256) void final_kernel(
    const int* __restrict__ labels, float* __restrict__ W, float* __restrict__ out)
{
    int tid = threadIdx.x;
    __shared__ float mats[3][64][65];
    __shared__ float mmL[2][4][64], ssL[2][4][64];
    __shared__ float cearr[6][64];
    __shared__ float cemoco[128];

    for (int idx = tid; idx < 3*4096; idx += 256) {
        int t = idx >> 12, rem = idx & 4095;
        const float* src = W + (t==0 ? WS_SIM : (t==1 ? WS_S0 : WS_S2));
        mats[t][rem>>6][rem&63] = src[rem];
    }

    {
        int g = tid >> 6, r = tid & 63;
        for (int mu=0; mu<2; mu++) {
            float m = -1e30f, s = 0.f;
            for (int k=0; k<32; k++) {
                int ch = g*32 + k;
                float om = W[WS_PM + mu*8192 + ch*64 + r];
                float os = W[WS_PS + mu*8192 + ch*64 + r];
                float nm = fmaxf(m, om);
                s = s*__expf(m-nm) + os*__expf(om-nm);
                m = nm;
            }
            mmL[mu][g][r] = m; ssL[mu][g][r] = s;
        }
    }
    __syncthreads();

    if (tid < 128) {
        int mu = tid>>6, r = tid&63;
        float m = mmL[mu][0][r], s = ssL[mu][0][r];
        for (int g=1; g<4; g++) {
            float om = mmL[mu][g][r], os = ssL[mu][g][r];
            float nm = fmaxf(m, om);
            s = s*__expf(m-nm) + os*__expf(om-nm);
            m = nm;
        }
        const float* AT = W + (mu ? WS_RNT : WS_CNT);
        const float* BT = W + (mu ? WS_CANT : WS_RANT);
        float dot = 0.f;
        for (int c=0; c<256; c++) dot += AT[c*64 + r]*BT[c*64 + r];
        float v0 = dot*INV_T;
        float nm = fmaxf(m, v0);
        float S = s*__expf(m-nm) + __expf(v0-nm);
        cemoco[tid] = nm + __logf(S) - v0;
    }

    for (int pass=0; pass<2; pass++) {
        int cfg = pass*4 + (tid>>6);
        int row = tid&63;
        if (cfg < 6) {
            int mi; float scale; int colMajor;
            if (cfg==0){ mi=0; scale=G3c; colMajor=1; }
            else if (cfg==1){ mi=0; scale=G3c; colMajor=0; }
            else if (cfg==2){ mi=1; scale=1.f; colMajor=0; }
            else if (cfg==3){ mi=1; scale=1.f; colMajor=1; }
            else if (cfg==4){ mi=2; scale=1.f; colMajor=0; }
            else            { mi=2; scale=1.f; colMajor=1; }
            float mx = -1e30f;
            for (int x=0;x<64;x++) {
                float v = (colMajor? mats[mi][x][row] : mats[mi][row][x])*scale;
                mx = fmaxf(mx, v);
            }
            float se = 0.f;
            for (int x=0;x<64;x++) {
                float v = (colMajor? mats[mi][x][row] : mats[mi][row][x])*scale;
                se += __expf(v-mx);
            }
            int lbl = labels[row];
            float diag = (colMajor? mats[mi][lbl][row] : mats[mi][row][lbl])*scale;
            cearr[cfg][row] = mx + __logf(se) - diag;
        }
    }
    __syncthreads();

    if (tid < 7) {
        float r;
        if (tid == 4) {
            float s0=0.f, s1=0.f;
            for (int k=0;k<64;k++){ s0 += cemoco[k]; s1 += cemoco[64+k]; }
            r = (s0/64.f + s1/64.f)*0.5f;
        } else {
            int cfg = (tid < 4) ? tid : tid - 1;
            float s = 0.f;
            for (int k=0;k<64;k++) s += cearr[cfg][k];
            r = s/64.f;
        }
        out[tid] = r;
    }
}

// ---------------------------------------------------------------------------
extern "C" void kernel_launch(void* const* d_in, const int* in_sizes, int n_in,
                              void* d_out, int out_size, void* d_ws, size_t ws_size,
                              hipStream_t stream)
{
    const float* cnn   = (const float*)d_in[0];
    const float* rnn   = (const float*)d_in[1];
    const float* img   = (const float*)d_in[2];
    const float* wemb  = (const float*)d_in[3];
    const float* cnnA  = (const float*)d_in[4];
    const float* rnnA  = (const float*)d_in[5];
    const float* queue   = (const float*)d_in[6];
    const float* queueIm = (const float*)d_in[7];
    const int*   labels  = (const int*)d_in[9];
    float* W   = (float*)d_ws;
    float* out = (float*)d_out;

    prep_kernel<<<1664, 256, 0, stream>>>(cnn, rnn, img, wemb, cnnA, rnnA, W);
    attn_moco_kernel<<<2368, 256, 0, stream>>>(queue, queueIm, W);
    final_kernel<<<1, 256, 0, stream>>>(labels, W, out);
}